// Round 2
// baseline (161.022 us; speedup 1.0000x reference)
//
#include <hip/hip_runtime.h>
#include <stdint.h>

#define BB 8
#define NN 2048
#define CC 128
#define DD 32
#define LOG2E 1.44269504088896340736f

typedef __attribute__((ext_vector_type(8))) short short8;
typedef __attribute__((ext_vector_type(4))) short short4v;
typedef __attribute__((ext_vector_type(4))) float f32x4;

#define MFMA(a,b,c) __builtin_amdgcn_mfma_f32_16x16x32_bf16(a,b,c,0,0,0)

__device__ __forceinline__ short f2b(float f){
  uint32_t u = __float_as_uint(f);
  uint32_t r = (u + 0x7fffu + ((u >> 16) & 1u)) >> 16;
  return (short)r;
}

// ---------------- kernel 0: pack weights, fold BN ----------------
__global__ void k_pack(const float* __restrict__ Wq, const float* __restrict__ Wk,
                       const float* __restrict__ Wv, const float* __restrict__ Wp,
                       const float* __restrict__ g, const float* __restrict__ bt,
                       const float* __restrict__ mu, const float* __restrict__ vr,
                       short* __restrict__ wqkv, short* __restrict__ wp,
                       float* __restrict__ scale, float* __restrict__ shift){
  int i = blockIdx.x*256 + threadIdx.x;
  if (i < 192*128){
    int r = i >> 7, c = i & 127;
    float w = (r < 32) ? Wq[r*128+c] : (r < 64) ? Wk[(r-32)*128+c] : Wv[(r-64)*128+c];
    wqkv[i] = f2b(w);
  }
  if (i < 128*128) wp[i] = f2b(Wp[i]);
  if (i < 128){
    float s = g[i] * rsqrtf(vr[i] + 1e-5f);
    scale[i] = s;
    shift[i] = bt[i] - mu[i]*s;
  }
}

// ---------------- kernel 1: QKV projections (MFMA) ----------------
// out: qb [B*N][32] bf16, kb [B*N][32] bf16, vt [B][C][N] bf16 (V transposed)
__global__ __launch_bounds__(256) void k_qkv(const float* __restrict__ x, const short* __restrict__ wqkv,
    short* __restrict__ qb, short* __restrict__ kb, short* __restrict__ vt){
  const int tid = threadIdx.x;
  const int wv = tid >> 6, l = tid & 63, lrow = l & 15, lg = l >> 4;
  const int r0 = blockIdx.x*64 + wv*16;
  const float* xr = x + (long)(r0 + lrow)*CC;
  short8 a[4];
  #pragma unroll
  for (int ks=0; ks<4; ks++){
    f32x4 u0 = *(const f32x4*)(xr + ks*32 + lg*8);
    f32x4 u1 = *(const f32x4*)(xr + ks*32 + lg*8 + 4);
    short8 t;
    #pragma unroll
    for (int j=0;j<4;j++){ t[j] = f2b(u0[j]); t[4+j] = f2b(u1[j]); }
    a[ks] = t;
  }
  f32x4 acc[12];
  #pragma unroll
  for (int i=0;i<12;i++) acc[i] = f32x4{0.f,0.f,0.f,0.f};
  #pragma unroll
  for (int of=0; of<12; of++){
    #pragma unroll
    for (int ks=0; ks<4; ks++){
      short8 bfr = *(const short8*)(wqkv + (of*16 + lrow)*CC + ks*32 + lg*8);
      acc[of] = MFMA(a[ks], bfr, acc[of]);
    }
  }
  const int b = r0 / NN, nin = r0 % NN;
  #pragma unroll
  for (int of=0; of<12; of++){
    const int o = of*16 + lrow;
    if (of < 2){
      #pragma unroll
      for (int rr=0; rr<4; rr++) qb[(long)(r0 + lg*4 + rr)*DD + o] = f2b(acc[of][rr]);
    } else if (of < 4){
      #pragma unroll
      for (int rr=0; rr<4; rr++) kb[(long)(r0 + lg*4 + rr)*DD + (o-32)] = f2b(acc[of][rr]);
    } else {
      short4v s;
      #pragma unroll
      for (int rr=0; rr<4; rr++) s[rr] = f2b(acc[of][rr]);
      *(short4v*)(vt + (long)(b*CC + (o-64))*NN + nin + lg*4) = s;
    }
  }
}

// ---------------- kernel 2: per-key column sum of exp(E) ----------------
// swapped operands: A = K rows (16 m), B = Q rows; lane sums over its n-columns
__global__ __launch_bounds__(256) void k_colsum(const short* __restrict__ qb, const short* __restrict__ kb,
                                                float* __restrict__ sinv){
  const int tid = threadIdx.x;
  const int wv = tid >> 6, l = tid & 63, lrow = l & 15, lg = l >> 4;
  const int b = blockIdx.x >> 5;
  const int m0 = (blockIdx.x & 31)*64 + wv*16;
  short8 afr = *(const short8*)(kb + (long)(b*NN + m0 + lrow)*DD + lg*8);
  const short* qbase = qb + (long)b*NN*DD;
  float sum[4] = {0.f,0.f,0.f,0.f};
  f32x4 z = {0.f,0.f,0.f,0.f};
  for (int n0=0; n0<NN; n0+=16){
    short8 bfr = *(const short8*)(qbase + (long)(n0 + lrow)*DD + lg*8);
    f32x4 e = MFMA(afr, bfr, z);
    #pragma unroll
    for (int r=0;r<4;r++) sum[r] += exp2f(e[r]*LOG2E);
  }
  #pragma unroll
  for (int mask=1; mask<16; mask<<=1){
    #pragma unroll
    for (int r=0;r<4;r++) sum[r] += __shfl_xor(sum[r], mask);
  }
  if (lrow == 0){
    #pragma unroll
    for (int r=0;r<4;r++) sinv[b*NN + m0 + lg*4 + r] = 1.0f / sum[r];
  }
}

// ---------------- kernel 3: row pass + PV + projection + BN + residual ----------------
// WG: 256 thr (4 waves x 16 rows), 64 rows of one batch. Loop keys in steps of 64.
// LDS: double-buffered {vt_tile [128][72], kb_tile [64][40]} + per-wave P [16][72]
__global__ __launch_bounds__(256) void k_attn(const float* __restrict__ x, const short* __restrict__ qb,
    const short* __restrict__ kb, const short* __restrict__ vt, const float* __restrict__ sinv,
    const short* __restrict__ wp, const float* __restrict__ scale, const float* __restrict__ shift,
    float* __restrict__ out){
  __shared__ __align__(16) short lds[28160]; // 2*11776 (tiles) + 4*1152 (P) shorts
  const int tid = threadIdx.x;
  const int wv = tid >> 6, l = tid & 63, lrow = l & 15, lg = l >> 4;
  const int b = blockIdx.x >> 5;
  const int n0 = (blockIdx.x & 31)*64 + wv*16;
  short8 qfr = *(const short8*)(qb + (long)(b*NN + n0 + lrow)*DD + lg*8);
  const short* kbb = kb + (long)b*NN*DD;
  const short* vtb = vt + (long)b*CC*NN;
  const float* sb = sinv + b*NN;

  f32x4 acc[8];
  #pragma unroll
  for (int i=0;i<8;i++) acc[i] = f32x4{0.f,0.f,0.f,0.f};
  float L[4] = {0.f,0.f,0.f,0.f};

  short8 sv[4]; short8 sk[2];
  const int cr = tid >> 1, hf = tid & 1;

  auto loadT = [&](int m0){
    const short* s = vtb + (long)cr*NN + m0 + hf*32;
    sv[0] = *(const short8*)(s);
    sv[1] = *(const short8*)(s+8);
    sv[2] = *(const short8*)(s+16);
    sv[3] = *(const short8*)(s+24);
    if (tid < 128){
      const short* s2 = kbb + (long)(m0 + cr)*DD + hf*16;
      sk[0] = *(const short8*)(s2);
      sk[1] = *(const short8*)(s2+8);
    }
  };
  auto storeT = [&](int buf){
    short* vt_t = lds + buf*11776;
    *(short8*)(vt_t + cr*72 + hf*32 + 0)  = sv[0];
    *(short8*)(vt_t + cr*72 + hf*32 + 8)  = sv[1];
    *(short8*)(vt_t + cr*72 + hf*32 + 16) = sv[2];
    *(short8*)(vt_t + cr*72 + hf*32 + 24) = sv[3];
    if (tid < 128){
      short* kb_t = vt_t + 9216;
      *(short8*)(kb_t + cr*40 + hf*16 + 0) = sk[0];
      *(short8*)(kb_t + cr*40 + hf*16 + 8) = sk[1];
    }
  };

  loadT(0);
  storeT(0);
  __syncthreads();

  short* pl = lds + 23552 + wv*1152;
  f32x4 z = {0.f,0.f,0.f,0.f};
  for (int it=0; it<32; it++){
    const int m0 = it*64;
    const int cur = it & 1;
    if (it < 31) loadT(m0 + 64);
    short* vt_t = lds + cur*11776;
    short* kb_t = vt_t + 9216;
    float p[16];
    #pragma unroll
    for (int mt=0; mt<4; mt++){
      short8 bfr = *(short8*)(kb_t + (mt*16 + lrow)*40 + lg*8);
      f32x4 e = MFMA(qfr, bfr, z);
      float si = sb[m0 + mt*16 + lrow];
      #pragma unroll
      for (int r=0;r<4;r++) p[mt*4+r] = exp2f(e[r]*LOG2E) * si;
    }
    #pragma unroll
    for (int r=0;r<4;r++) L[r] += (p[r] + p[4+r]) + (p[8+r] + p[12+r]);
    #pragma unroll
    for (int mt=0; mt<4; mt++){
      #pragma unroll
      for (int r=0;r<4;r++)
        pl[(lg*4+r)*72 + mt*16 + lrow] = f2b(p[mt*4+r]);
    }
    #pragma unroll
    for (int ks=0; ks<2; ks++){
      short8 pa = *(short8*)(pl + lrow*72 + ks*32 + lg*8);
      #pragma unroll
      for (int cf=0; cf<8; cf++){
        short8 vb_ = *(short8*)(vt_t + (cf*16 + lrow)*72 + ks*32 + lg*8);
        acc[cf] = MFMA(pa, vb_, acc[cf]);
      }
    }
    if (it < 31) storeT((it+1) & 1);
    __syncthreads();
  }

  // ---- epilogue ----
  #pragma unroll
  for (int mask=1; mask<16; mask<<=1){
    #pragma unroll
    for (int r=0;r<4;r++) L[r] += __shfl_xor(L[r], mask);
  }
  float linv[4];
  #pragma unroll
  for (int r=0;r<4;r++) linv[r] = 1.0f / (1e-9f + L[r]);

  const float* xbb = x + (long)(b*NN + n0)*CC;
  float xv[32];
  short* dl = lds + wv*2176;   // reuse tile region (all waves past final barrier)
  #pragma unroll
  for (int cf=0; cf<8; cf++){
    #pragma unroll
    for (int r=0;r<4;r++){
      float xx = xbb[(lg*4+r)*CC + cf*16 + lrow];
      xv[cf*4+r] = xx;
      dl[(lg*4+r)*136 + cf*16 + lrow] = f2b(xx - acc[cf][r]*linv[r]);
    }
  }
  f32x4 yac[8];
  #pragma unroll
  for (int i=0;i<8;i++) yac[i] = f32x4{0.f,0.f,0.f,0.f};
  #pragma unroll
  for (int ks=0; ks<4; ks++){
    short8 da = *(short8*)(dl + lrow*136 + ks*32 + lg*8);
    #pragma unroll
    for (int of=0; of<8; of++){
      short8 wfr = *(const short8*)(wp + (of*16 + lrow)*CC + ks*32 + lg*8);
      yac[of] = MFMA(da, wfr, yac[of]);
    }
  }
  float* ob = out + (long)(b*NN + n0)*CC;
  #pragma unroll
  for (int of=0; of<8; of++){
    const int o = of*16 + lrow;
    const float sc = scale[o], sh = shift[o];
    #pragma unroll
    for (int r=0;r<4;r++){
      float y = yac[of][r]*sc + sh;
      y = (y >= 0.f) ? y : 0.01f*y;
      ob[(lg*4+r)*CC + o] = y + xv[of*4+r];
    }
  }
}

extern "C" void kernel_launch(void* const* d_in, const int* in_sizes, int n_in,
                              void* d_out, int out_size, void* d_ws, size_t ws_size,
                              hipStream_t stream) {
  const float* x  = (const float*)d_in[0];
  const float* Wq = (const float*)d_in[1];
  const float* Wk = (const float*)d_in[2];
  const float* Wv = (const float*)d_in[3];
  const float* Wp = (const float*)d_in[4];
  const float* g  = (const float*)d_in[5];
  const float* bt = (const float*)d_in[6];
  const float* mu = (const float*)d_in[7];
  const float* vr = (const float*)d_in[8];
  float* out = (float*)d_out;

  char* ws = (char*)d_ws;
  short* wqkv  = (short*)(ws + 0);            // 192*128*2 = 49152
  short* wp    = (short*)(ws + 49152);        // 128*128*2 = 32768
  float* scale = (float*)(ws + 81920);        // 512
  float* shift = (float*)(ws + 82432);        // 512
  short* qb    = (short*)(ws + 98304);        // 16384*32*2 = 1 MB
  short* kb    = (short*)(ws + 98304 + 1048576);
  short* vt    = (short*)(ws + 98304 + 2097152);   // 8*128*2048*2 = 4 MB
  float* sinv  = (float*)(ws + 98304 + 6291456);   // 64 KB

  k_pack<<<96, 256, 0, stream>>>(Wq, Wk, Wv, Wp, g, bt, mu, vr, wqkv, wp, scale, shift);
  k_qkv<<<256, 256, 0, stream>>>(x, wqkv, qb, kb, vt);
  k_colsum<<<256, 256, 0, stream>>>(qb, kb, sinv);
  k_attn<<<256, 256, 0, stream>>>(x, qb, kb, vt, sinv, wp, scale, shift, out);
}

// Round 3
// 153.433 us; speedup vs baseline: 1.0495x; 1.0495x over previous
//
#include <hip/hip_runtime.h>
#include <stdint.h>

#define BB 8
#define NN 2048
#define CC 128
#define DD 32
#define LOG2E 1.44269504088896340736f

typedef __attribute__((ext_vector_type(8))) short short8;
typedef __attribute__((ext_vector_type(4))) short short4v;
typedef __attribute__((ext_vector_type(4))) float f32x4;

#define MFMA(a,b,c) __builtin_amdgcn_mfma_f32_16x16x32_bf16(a,b,c,0,0,0)

__device__ __forceinline__ short f2b(float f){
  uint32_t u = __float_as_uint(f);
  uint32_t r = (u + 0x7fffu + ((u >> 16) & 1u)) >> 16;
  return (short)r;
}

// ---------------- kernel 0: pack weights, fold BN ----------------
__global__ void k_pack(const float* __restrict__ Wq, const float* __restrict__ Wk,
                       const float* __restrict__ Wv, const float* __restrict__ Wp,
                       const float* __restrict__ g, const float* __restrict__ bt,
                       const float* __restrict__ mu, const float* __restrict__ vr,
                       short* __restrict__ wqkv, short* __restrict__ wp,
                       float* __restrict__ scale, float* __restrict__ shift){
  int i = blockIdx.x*256 + threadIdx.x;
  if (i < 192*128){
    int r = i >> 7, c = i & 127;
    float w = (r < 32) ? Wq[r*128+c] : (r < 64) ? Wk[(r-32)*128+c] : Wv[(r-64)*128+c];
    wqkv[i] = f2b(w);
  }
  if (i < 128*128) wp[i] = f2b(Wp[i]);
  if (i < 128){
    float s = g[i] * rsqrtf(vr[i] + 1e-5f);
    scale[i] = s;
    shift[i] = bt[i] - mu[i]*s;
  }
}

// ---------------- kernel 1: QKV projections (MFMA) ----------------
__global__ __launch_bounds__(256) void k_qkv(const float* __restrict__ x, const short* __restrict__ wqkv,
    short* __restrict__ qb, short* __restrict__ kb, short* __restrict__ vt){
  const int tid = threadIdx.x;
  const int wv = tid >> 6, l = tid & 63, lrow = l & 15, lg = l >> 4;
  const int r0 = blockIdx.x*64 + wv*16;
  const float* xr = x + (long)(r0 + lrow)*CC;
  short8 a[4];
  #pragma unroll
  for (int ks=0; ks<4; ks++){
    f32x4 u0 = *(const f32x4*)(xr + ks*32 + lg*8);
    f32x4 u1 = *(const f32x4*)(xr + ks*32 + lg*8 + 4);
    short8 t;
    #pragma unroll
    for (int j=0;j<4;j++){ t[j] = f2b(u0[j]); t[4+j] = f2b(u1[j]); }
    a[ks] = t;
  }
  f32x4 acc[12];
  #pragma unroll
  for (int i=0;i<12;i++) acc[i] = f32x4{0.f,0.f,0.f,0.f};
  #pragma unroll
  for (int of=0; of<12; of++){
    #pragma unroll
    for (int ks=0; ks<4; ks++){
      short8 bfr = *(const short8*)(wqkv + (of*16 + lrow)*CC + ks*32 + lg*8);
      acc[of] = MFMA(a[ks], bfr, acc[of]);
    }
  }
  const int b = r0 / NN, nin = r0 % NN;
  #pragma unroll
  for (int of=0; of<12; of++){
    const int o = of*16 + lrow;
    if (of < 2){
      #pragma unroll
      for (int rr=0; rr<4; rr++) qb[(long)(r0 + lg*4 + rr)*DD + o] = f2b(acc[of][rr]);
    } else if (of < 4){
      #pragma unroll
      for (int rr=0; rr<4; rr++) kb[(long)(r0 + lg*4 + rr)*DD + (o-32)] = f2b(acc[of][rr]);
    } else {
      short4v s;
      #pragma unroll
      for (int rr=0; rr<4; rr++) s[rr] = f2b(acc[of][rr]);
      *(short4v*)(vt + (long)(b*CC + (o-64))*NN + nin + lg*4) = s;
    }
  }
}

// ---------------- kernel 2: per-key column sum of exp(E), 2-way n-split ----------------
// grid 512: b(3b) | half(1b) | mblock(5b)
__global__ __launch_bounds__(256) void k_colsum(const short* __restrict__ qb, const short* __restrict__ kb,
                                                float* __restrict__ csum){
  const int tid = threadIdx.x;
  const int wv = tid >> 6, l = tid & 63, lrow = l & 15, lg = l >> 4;
  const int b = blockIdx.x >> 6;
  const int half = (blockIdx.x >> 5) & 1;
  const int m0 = (blockIdx.x & 31)*64 + wv*16;
  short8 afr = *(const short8*)(kb + (long)(b*NN + m0 + lrow)*DD + lg*8);
  const short* qbase = qb + (long)b*NN*DD;
  float sum[4] = {0.f,0.f,0.f,0.f};
  f32x4 z = {0.f,0.f,0.f,0.f};
  const int nbeg = half*1024, nend = nbeg + 1024;
  for (int n0=nbeg; n0<nend; n0+=16){
    short8 bfr = *(const short8*)(qbase + (long)(n0 + lrow)*DD + lg*8);
    f32x4 e = MFMA(afr, bfr, z);
    #pragma unroll
    for (int r=0;r<4;r++) sum[r] += exp2f(e[r]*LOG2E);
  }
  #pragma unroll
  for (int mask=1; mask<16; mask<<=1){
    #pragma unroll
    for (int r=0;r<4;r++) sum[r] += __shfl_xor(sum[r], mask);
  }
  if (lrow == 0){
    #pragma unroll
    for (int r=0;r<4;r++) csum[half*(BB*NN) + b*NN + m0 + lg*4 + r] = sum[r];
  }
}

// ---------------- kernel 3a: split attention pass (keys halved) ----------------
// grid 512: b(3b) | half(1b) | rowtile(5b). Writes fp32 partial acc + partial L.
__global__ __launch_bounds__(256) void k_attn(const short* __restrict__ qb,
    const short* __restrict__ kb, const short* __restrict__ vt, const float* __restrict__ csum,
    float* __restrict__ accP, float* __restrict__ Lp){
  __shared__ __align__(16) short lds[28160];
  const int tid = threadIdx.x;
  const int wv = tid >> 6, l = tid & 63, lrow = l & 15, lg = l >> 4;
  const int b = blockIdx.x >> 6;
  const int half = (blockIdx.x >> 5) & 1;
  const int rt = blockIdx.x & 31;
  const int n0 = rt*64 + wv*16;
  short8 qfr = *(const short8*)(qb + (long)(b*NN + n0 + lrow)*DD + lg*8);
  const short* kbb = kb + (long)b*NN*DD;
  const short* vtb = vt + (long)b*CC*NN;
  const float* c0 = csum + b*NN;
  const float* c1 = c0 + BB*NN;

  f32x4 acc[8];
  #pragma unroll
  for (int i=0;i<8;i++) acc[i] = f32x4{0.f,0.f,0.f,0.f};
  float L[4] = {0.f,0.f,0.f,0.f};

  short8 sv[4]; short8 sk[2];
  const int cr = tid >> 1, hf = tid & 1;

  auto loadT = [&](int m0){
    const short* s = vtb + (long)cr*NN + m0 + hf*32;
    sv[0] = *(const short8*)(s);
    sv[1] = *(const short8*)(s+8);
    sv[2] = *(const short8*)(s+16);
    sv[3] = *(const short8*)(s+24);
    if (tid < 128){
      const short* s2 = kbb + (long)(m0 + cr)*DD + hf*16;
      sk[0] = *(const short8*)(s2);
      sk[1] = *(const short8*)(s2+8);
    }
  };
  auto storeT = [&](int buf){
    short* vt_t = lds + buf*11776;
    *(short8*)(vt_t + cr*72 + hf*32 + 0)  = sv[0];
    *(short8*)(vt_t + cr*72 + hf*32 + 8)  = sv[1];
    *(short8*)(vt_t + cr*72 + hf*32 + 16) = sv[2];
    *(short8*)(vt_t + cr*72 + hf*32 + 24) = sv[3];
    if (tid < 128){
      short* kb_t = vt_t + 9216;
      *(short8*)(kb_t + cr*40 + hf*16 + 0) = sk[0];
      *(short8*)(kb_t + cr*40 + hf*16 + 8) = sk[1];
    }
  };

  const int mbase = half*1024;
  loadT(mbase);
  storeT(0);
  __syncthreads();

  short* pl = lds + 23552 + wv*1152;
  f32x4 z = {0.f,0.f,0.f,0.f};
  for (int it=0; it<16; it++){
    const int m0 = mbase + it*64;
    const int cur = it & 1;
    if (it < 15) loadT(m0 + 64);
    short* vt_t = lds + cur*11776;
    short* kb_t = vt_t + 9216;
    float p[16];
    #pragma unroll
    for (int mt=0; mt<4; mt++){
      short8 bfr = *(short8*)(kb_t + (mt*16 + lrow)*40 + lg*8);
      f32x4 e = MFMA(qfr, bfr, z);
      const int m = m0 + mt*16 + lrow;
      float si = __builtin_amdgcn_rcpf(c0[m] + c1[m]);
      #pragma unroll
      for (int r=0;r<4;r++) p[mt*4+r] = exp2f(e[r]*LOG2E) * si;
    }
    #pragma unroll
    for (int r=0;r<4;r++) L[r] += (p[r] + p[4+r]) + (p[8+r] + p[12+r]);
    #pragma unroll
    for (int mt=0; mt<4; mt++){
      #pragma unroll
      for (int r=0;r<4;r++)
        pl[(lg*4+r)*72 + mt*16 + lrow] = f2b(p[mt*4+r]);
    }
    #pragma unroll
    for (int ks=0; ks<2; ks++){
      short8 pa = *(short8*)(pl + lrow*72 + ks*32 + lg*8);
      #pragma unroll
      for (int cf=0; cf<8; cf++){
        short8 vb_ = *(short8*)(vt_t + (cf*16 + lrow)*72 + ks*32 + lg*8);
        acc[cf] = MFMA(pa, vb_, acc[cf]);
      }
    }
    if (it < 15) storeT((it+1) & 1);
    __syncthreads();
  }

  #pragma unroll
  for (int mask=1; mask<16; mask<<=1){
    #pragma unroll
    for (int r=0;r<4;r++) L[r] += __shfl_xor(L[r], mask);
  }

  const long tile = (long)((b*32 + rt)*2 + half);
  float* aP = accP + tile*64*128;
  #pragma unroll
  for (int cf=0; cf<8; cf++){
    #pragma unroll
    for (int r=0;r<4;r++)
      aP[(wv*16 + lg*4 + r)*128 + cf*16 + lrow] = acc[cf][r];
  }
  if (lrow == 0){
    #pragma unroll
    for (int r=0;r<4;r++) Lp[tile*64 + wv*16 + lg*4 + r] = L[r];
  }
}

// ---------------- kernel 3b: combine halves + projection + BN + residual ----------------
__global__ __launch_bounds__(256) void k_fin(const float* __restrict__ x, const float* __restrict__ accP,
    const float* __restrict__ Lp, const short* __restrict__ wp, const float* __restrict__ scale,
    const float* __restrict__ shift, float* __restrict__ out){
  __shared__ __align__(16) short lds[8704];
  const int tid = threadIdx.x;
  const int wv = tid >> 6, l = tid & 63, lrow = l & 15, lg = l >> 4;
  const int b = blockIdx.x >> 5;
  const int rt = blockIdx.x & 31;
  const long tile = (long)((b*32 + rt)*2);
  const float* a0 = accP + tile*64*128 + wv*16*128;
  const float* a1 = a0 + 64*128;
  const float* L0 = Lp + tile*64 + wv*16;
  const float* L1 = L0 + 64;
  float linv[4];
  #pragma unroll
  for (int r=0;r<4;r++){
    float Ls = L0[lg*4+r] + L1[lg*4+r];
    linv[r] = __builtin_amdgcn_rcpf(1e-9f + Ls);
  }
  const float* xbb = x + (long)(b*NN + rt*64 + wv*16)*CC;
  float xv[32];
  short* dl = lds + wv*2176;
  #pragma unroll
  for (int cf=0; cf<8; cf++){
    #pragma unroll
    for (int r=0;r<4;r++){
      const int row = lg*4+r, col = cf*16+lrow;
      float xx = xbb[row*CC + col];
      xv[cf*4+r] = xx;
      float a = a0[row*128+col] + a1[row*128+col];
      dl[row*136 + col] = f2b(xx - a*linv[r]);
    }
  }
  f32x4 yac[8];
  #pragma unroll
  for (int i=0;i<8;i++) yac[i] = f32x4{0.f,0.f,0.f,0.f};
  #pragma unroll
  for (int ks=0; ks<4; ks++){
    short8 da = *(short8*)(dl + lrow*136 + ks*32 + lg*8);
    #pragma unroll
    for (int of=0; of<8; of++){
      short8 wfr = *(const short8*)(wp + (of*16 + lrow)*CC + ks*32 + lg*8);
      yac[of] = MFMA(da, wfr, yac[of]);
    }
  }
  float* ob = out + (long)(b*NN + rt*64 + wv*16)*CC;
  #pragma unroll
  for (int of=0; of<8; of++){
    const int o = of*16 + lrow;
    const float sc = scale[o], sh = shift[o];
    #pragma unroll
    for (int r=0;r<4;r++){
      float y = yac[of][r]*sc + sh;
      y = (y >= 0.f) ? y : 0.01f*y;
      ob[(lg*4+r)*CC + o] = y + xv[of*4+r];
    }
  }
}

// ---------------- fallback: monolithic attention (only if ws too small) ----------------
__global__ __launch_bounds__(256) void k_attn_mono(const float* __restrict__ x, const short* __restrict__ qb,
    const short* __restrict__ kb, const short* __restrict__ vt, const float* __restrict__ csum,
    const short* __restrict__ wp, const float* __restrict__ scale, const float* __restrict__ shift,
    float* __restrict__ out){
  __shared__ __align__(16) short lds[28160];
  const int tid = threadIdx.x;
  const int wv = tid >> 6, l = tid & 63, lrow = l & 15, lg = l >> 4;
  const int b = blockIdx.x >> 5;
  const int n0 = (blockIdx.x & 31)*64 + wv*16;
  short8 qfr = *(const short8*)(qb + (long)(b*NN + n0 + lrow)*DD + lg*8);
  const short* kbb = kb + (long)b*NN*DD;
  const short* vtb = vt + (long)b*CC*NN;
  const float* c0 = csum + b*NN;
  const float* c1 = c0 + BB*NN;

  f32x4 acc[8];
  #pragma unroll
  for (int i=0;i<8;i++) acc[i] = f32x4{0.f,0.f,0.f,0.f};
  float L[4] = {0.f,0.f,0.f,0.f};
  short8 sv[4]; short8 sk[2];
  const int cr = tid >> 1, hf = tid & 1;
  auto loadT = [&](int m0){
    const short* s = vtb + (long)cr*NN + m0 + hf*32;
    sv[0] = *(const short8*)(s); sv[1] = *(const short8*)(s+8);
    sv[2] = *(const short8*)(s+16); sv[3] = *(const short8*)(s+24);
    if (tid < 128){
      const short* s2 = kbb + (long)(m0 + cr)*DD + hf*16;
      sk[0] = *(const short8*)(s2); sk[1] = *(const short8*)(s2+8);
    }
  };
  auto storeT = [&](int buf){
    short* vt_t = lds + buf*11776;
    *(short8*)(vt_t + cr*72 + hf*32 + 0)  = sv[0];
    *(short8*)(vt_t + cr*72 + hf*32 + 8)  = sv[1];
    *(short8*)(vt_t + cr*72 + hf*32 + 16) = sv[2];
    *(short8*)(vt_t + cr*72 + hf*32 + 24) = sv[3];
    if (tid < 128){
      short* kb_t = vt_t + 9216;
      *(short8*)(kb_t + cr*40 + hf*16 + 0) = sk[0];
      *(short8*)(kb_t + cr*40 + hf*16 + 8) = sk[1];
    }
  };
  loadT(0); storeT(0); __syncthreads();
  short* pl = lds + 23552 + wv*1152;
  f32x4 z = {0.f,0.f,0.f,0.f};
  for (int it=0; it<32; it++){
    const int m0 = it*64;
    const int cur = it & 1;
    if (it < 31) loadT(m0 + 64);
    short* vt_t = lds + cur*11776;
    short* kb_t = vt_t + 9216;
    float p[16];
    #pragma unroll
    for (int mt=0; mt<4; mt++){
      short8 bfr = *(short8*)(kb_t + (mt*16 + lrow)*40 + lg*8);
      f32x4 e = MFMA(qfr, bfr, z);
      const int m = m0 + mt*16 + lrow;
      float si = __builtin_amdgcn_rcpf(c0[m] + c1[m]);
      #pragma unroll
      for (int r=0;r<4;r++) p[mt*4+r] = exp2f(e[r]*LOG2E) * si;
    }
    #pragma unroll
    for (int r=0;r<4;r++) L[r] += (p[r] + p[4+r]) + (p[8+r] + p[12+r]);
    #pragma unroll
    for (int mt=0; mt<4; mt++){
      #pragma unroll
      for (int r=0;r<4;r++)
        pl[(lg*4+r)*72 + mt*16 + lrow] = f2b(p[mt*4+r]);
    }
    #pragma unroll
    for (int ks=0; ks<2; ks++){
      short8 pa = *(short8*)(pl + lrow*72 + ks*32 + lg*8);
      #pragma unroll
      for (int cf=0; cf<8; cf++){
        short8 vb_ = *(short8*)(vt_t + (cf*16 + lrow)*72 + ks*32 + lg*8);
        acc[cf] = MFMA(pa, vb_, acc[cf]);
      }
    }
    if (it < 31) storeT((it+1) & 1);
    __syncthreads();
  }
  #pragma unroll
  for (int mask=1; mask<16; mask<<=1){
    #pragma unroll
    for (int r=0;r<4;r++) L[r] += __shfl_xor(L[r], mask);
  }
  float linv[4];
  #pragma unroll
  for (int r=0;r<4;r++) linv[r] = __builtin_amdgcn_rcpf(1e-9f + L[r]);
  const float* xbb = x + (long)(b*NN + n0)*CC;
  float xv[32];
  short* dl = lds + wv*2176;
  #pragma unroll
  for (int cf=0; cf<8; cf++){
    #pragma unroll
    for (int r=0;r<4;r++){
      float xx = xbb[(lg*4+r)*CC + cf*16 + lrow];
      xv[cf*4+r] = xx;
      dl[(lg*4+r)*136 + cf*16 + lrow] = f2b(xx - acc[cf][r]*linv[r]);
    }
  }
  f32x4 yac[8];
  #pragma unroll
  for (int i=0;i<8;i++) yac[i] = f32x4{0.f,0.f,0.f,0.f};
  #pragma unroll
  for (int ks=0; ks<4; ks++){
    short8 da = *(short8*)(dl + lrow*136 + ks*32 + lg*8);
    #pragma unroll
    for (int of=0; of<8; of++){
      short8 wfr = *(const short8*)(wp + (of*16 + lrow)*CC + ks*32 + lg*8);
      yac[of] = MFMA(da, wfr, yac[of]);
    }
  }
  float* ob = out + (long)(b*NN + n0)*CC;
  #pragma unroll
  for (int of=0; of<8; of++){
    const int o = of*16 + lrow;
    const float sc = scale[o], sh = shift[o];
    #pragma unroll
    for (int r=0;r<4;r++){
      float y = yac[of][r]*sc + sh;
      y = (y >= 0.f) ? y : 0.01f*y;
      ob[(lg*4+r)*CC + o] = y + xv[of*4+r];
    }
  }
}

extern "C" void kernel_launch(void* const* d_in, const int* in_sizes, int n_in,
                              void* d_out, int out_size, void* d_ws, size_t ws_size,
                              hipStream_t stream) {
  const float* x  = (const float*)d_in[0];
  const float* Wq = (const float*)d_in[1];
  const float* Wk = (const float*)d_in[2];
  const float* Wv = (const float*)d_in[3];
  const float* Wp = (const float*)d_in[4];
  const float* g  = (const float*)d_in[5];
  const float* bt = (const float*)d_in[6];
  const float* mu = (const float*)d_in[7];
  const float* vr = (const float*)d_in[8];
  float* out = (float*)d_out;

  char* ws = (char*)d_ws;
  short* wqkv  = (short*)(ws + 0);                  // 49152
  short* wp    = (short*)(ws + 49152);              // 32768
  float* scale = (float*)(ws + 81920);              // 512
  float* shift = (float*)(ws + 82432);              // 512
  short* qb    = (short*)(ws + 98304);              // 1 MB
  short* kb    = (short*)(ws + 98304 + 1048576);    // 1 MB
  short* vt    = (short*)(ws + 98304 + 2097152);    // 4 MB
  float* csum  = (float*)(ws + 98304 + 6291456);    // 2*16384*4 = 131072
  float* Lp    = (float*)(ws + 98304 + 6422528);    // 131072
  float* accP  = (float*)(ws + 98304 + 6553600);    // 16 MB
  const size_t need_split = 98304 + 6553600 + 16777216;

  k_pack<<<96, 256, 0, stream>>>(Wq, Wk, Wv, Wp, g, bt, mu, vr, wqkv, wp, scale, shift);
  k_qkv<<<256, 256, 0, stream>>>(x, wqkv, qb, kb, vt);
  k_colsum<<<512, 256, 0, stream>>>(qb, kb, csum);
  if (ws_size >= need_split){
    k_attn<<<512, 256, 0, stream>>>(qb, kb, vt, csum, accP, Lp);
    k_fin<<<256, 256, 0, stream>>>(x, accP, Lp, wp, scale, shift, out);
  } else {
    k_attn_mono<<<256, 256, 0, stream>>>(x, qb, kb, vt, csum, wp, scale, shift, out);
  }
}

// Round 5
// 133.870 us; speedup vs baseline: 1.2028x; 1.1461x over previous
//
#include <hip/hip_runtime.h>
#include <stdint.h>

#define BB 8
#define NN 2048
#define CC 128
#define DD 32
#define LOG2E 1.44269504088896340736f

typedef __attribute__((ext_vector_type(8))) short short8;
typedef __attribute__((ext_vector_type(4))) short short4v;
typedef __attribute__((ext_vector_type(4))) float f32x4;

#define MFMA(a,b,c) __builtin_amdgcn_mfma_f32_16x16x32_bf16(a,b,c,0,0,0)

__device__ __forceinline__ short f2b(float f){
  uint32_t u = __float_as_uint(f);
  uint32_t r = (u + 0x7fffu + ((u >> 16) & 1u)) >> 16;
  return (short)r;
}

// ---------------- kernel 0: pack weights, fold BN ----------------
__global__ void k_pack(const float* __restrict__ Wq, const float* __restrict__ Wk,
                       const float* __restrict__ Wv, const float* __restrict__ Wp,
                       const float* __restrict__ g, const float* __restrict__ bt,
                       const float* __restrict__ mu, const float* __restrict__ vr,
                       short* __restrict__ wqkv, short* __restrict__ wp,
                       float* __restrict__ scale, float* __restrict__ shift){
  int i = blockIdx.x*256 + threadIdx.x;
  if (i < 192*128){
    int r = i >> 7, c = i & 127;
    float w = (r < 32) ? Wq[r*128+c] : (r < 64) ? Wk[(r-32)*128+c] : Wv[(r-64)*128+c];
    wqkv[i] = f2b(w);
  }
  if (i < 128*128) wp[i] = f2b(Wp[i]);
  if (i < 128){
    float s = g[i] * rsqrtf(vr[i] + 1e-5f);
    scale[i] = s;
    shift[i] = bt[i] - mu[i]*s;
  }
}

// ---------------- kernel 1: QKV projections, grid 512 (32 rows/block) ----------------
// qb is pre-scaled by LOG2E so downstream uses exp2 directly.
__global__ __launch_bounds__(256,4) void k_qkv(const float* __restrict__ x, const short* __restrict__ wqkv,
    short* __restrict__ qb, short* __restrict__ kb, short* __restrict__ vt){
  const int tid = threadIdx.x;
  const int wv = tid >> 6, l = tid & 63, lrow = l & 15, lg = l >> 4;
  const int r0 = blockIdx.x*32 + (wv & 1)*16;
  const int base = (wv >> 1)*6;
  const float* xr = x + (long)(r0 + lrow)*CC;
  short8 a[4];
  #pragma unroll
  for (int ks=0; ks<4; ks++){
    f32x4 u0 = *(const f32x4*)(xr + ks*32 + lg*8);
    f32x4 u1 = *(const f32x4*)(xr + ks*32 + lg*8 + 4);
    short8 t;
    #pragma unroll
    for (int j=0;j<4;j++){ t[j] = f2b(u0[j]); t[4+j] = f2b(u1[j]); }
    a[ks] = t;
  }
  f32x4 acc[6];
  #pragma unroll
  for (int i=0;i<6;i++) acc[i] = f32x4{0.f,0.f,0.f,0.f};
  #pragma unroll
  for (int of=0; of<6; of++){
    #pragma unroll
    for (int ks=0; ks<4; ks++){
      short8 bfr = *(const short8*)(wqkv + ((base+of)*16 + lrow)*CC + ks*32 + lg*8);
      acc[of] = MFMA(a[ks], bfr, acc[of]);
    }
  }
  const int b = r0 / NN, nin = r0 % NN;
  #pragma unroll
  for (int of=0; of<6; of++){
    const int oo = base + of;
    const int o = oo*16 + lrow;
    if (oo < 2){
      #pragma unroll
      for (int rr=0; rr<4; rr++) qb[(long)(r0 + lg*4 + rr)*DD + o] = f2b(acc[of][rr]*LOG2E);
    } else if (oo < 4){
      #pragma unroll
      for (int rr=0; rr<4; rr++) kb[(long)(r0 + lg*4 + rr)*DD + (o-32)] = f2b(acc[of][rr]);
    } else {
      short4v s;
      #pragma unroll
      for (int rr=0; rr<4; rr++) s[rr] = f2b(acc[of][rr]);
      *(short4v*)(vt + (long)(b*CC + (o-64))*NN + nin + lg*4) = s;
    }
  }
}

// ---------------- kernel 2: column sums of exp(E), 4-way n-split ----------------
// grid 1024: b(3b) | quarter(2b) | mblock(5b)
__global__ __launch_bounds__(256,4) void k_colsum(const short* __restrict__ qb, const short* __restrict__ kb,
                                                  float* __restrict__ csum){
  const int tid = threadIdx.x;
  const int wv = tid >> 6, l = tid & 63, lrow = l & 15, lg = l >> 4;
  const int b = blockIdx.x >> 7;
  const int q = (blockIdx.x >> 5) & 3;
  const int m0 = (blockIdx.x & 31)*64 + wv*16;
  short8 afr = *(const short8*)(kb + (long)(b*NN + m0 + lrow)*DD + lg*8);
  const short* qbase = qb + (long)b*NN*DD;
  float sum[4] = {0.f,0.f,0.f,0.f};
  f32x4 z = {0.f,0.f,0.f,0.f};
  const int nbeg = q*512, nend = nbeg + 512;
  #pragma unroll 4
  for (int n0=nbeg; n0<nend; n0+=16){
    short8 bfr = *(const short8*)(qbase + (long)(n0 + lrow)*DD + lg*8);
    f32x4 e = MFMA(afr, bfr, z);
    #pragma unroll
    for (int r=0;r<4;r++) sum[r] += exp2f(e[r]);
  }
  #pragma unroll
  for (int mask=1; mask<16; mask<<=1){
    #pragma unroll
    for (int r=0;r<4;r++) sum[r] += __shfl_xor(sum[r], mask);
  }
  if (lrow == 0){
    #pragma unroll
    for (int r=0;r<4;r++) csum[q*(BB*NN) + b*NN + m0 + lg*4 + r] = sum[r];
  }
}

// ---------------- kernel 3a: attention pass, 4-way key split, single-buffer LDS ----------------
// grid 1024: b(3b) | quarter(2b) | rowtile(5b). LDS ~34.8 KB -> 4 blocks/CU.
__global__ __launch_bounds__(256,4) void k_attn(const short* __restrict__ qb,
    const short* __restrict__ kb, const short* __restrict__ vt, const float* __restrict__ csum,
    float* __restrict__ accP, float* __restrict__ Lp){
  __shared__ __align__(16) short lds[17408]; // tile 11776 + P 4*1152 + sinv 1024
  const int tid = threadIdx.x;
  const int wv = tid >> 6, l = tid & 63, lrow = l & 15, lg = l >> 4;
  const int b = blockIdx.x >> 7;
  const int quarter = (blockIdx.x >> 5) & 3;
  const int rt = blockIdx.x & 31;
  const int n0 = rt*64 + wv*16;
  short8 qfr = *(const short8*)(qb + (long)(b*NN + n0 + lrow)*DD + lg*8);
  const short* kbb = kb + (long)b*NN*DD;
  const short* vtb = vt + (long)b*CC*NN;
  float* sinvl = (float*)(lds + 16384);

  // combine 4 csum parts for this block's 512 keys into LDS
  const int mbase = quarter*512;
  {
    const float* c0 = csum + b*NN + mbase;
    #pragma unroll
    for (int i=tid; i<512; i+=256){
      float s = c0[i] + c0[i + BB*NN] + c0[i + 2*BB*NN] + c0[i + 3*BB*NN];
      sinvl[i] = __builtin_amdgcn_rcpf(s);
    }
  }

  f32x4 acc[8];
  #pragma unroll
  for (int i=0;i<8;i++) acc[i] = f32x4{0.f,0.f,0.f,0.f};
  float L[4] = {0.f,0.f,0.f,0.f};

  short8 sv[4]; short8 sk[2];
  const int cr = tid >> 1, hf = tid & 1;

  auto loadT = [&](int m0){
    const short* s = vtb + (long)cr*NN + m0 + hf*32;
    sv[0] = *(const short8*)(s);
    sv[1] = *(const short8*)(s+8);
    sv[2] = *(const short8*)(s+16);
    sv[3] = *(const short8*)(s+24);
    if (tid < 128){
      const short* s2 = kbb + (long)(m0 + cr)*DD + hf*16;
      sk[0] = *(const short8*)(s2);
      sk[1] = *(const short8*)(s2+8);
    }
  };
  auto storeT = [&](){
    short* vt_t = lds;
    *(short8*)(vt_t + cr*72 + hf*32 + 0)  = sv[0];
    *(short8*)(vt_t + cr*72 + hf*32 + 8)  = sv[1];
    *(short8*)(vt_t + cr*72 + hf*32 + 16) = sv[2];
    *(short8*)(vt_t + cr*72 + hf*32 + 24) = sv[3];
    if (tid < 128){
      short* kb_t = vt_t + 9216;
      *(short8*)(kb_t + cr*40 + hf*16 + 0) = sk[0];
      *(short8*)(kb_t + cr*40 + hf*16 + 8) = sk[1];
    }
  };

  loadT(mbase);
  storeT();
  __syncthreads();

  short* pl = lds + 11776 + wv*1152;
  f32x4 z = {0.f,0.f,0.f,0.f};
  for (int it=0; it<8; it++){
    const int m0 = mbase + it*64;
    if (it < 7) loadT(m0 + 64);
    short* vt_t = lds;
    short* kb_t = lds + 9216;
    float p[16];
    #pragma unroll
    for (int mt=0; mt<4; mt++){
      short8 bfr = *(short8*)(kb_t + (mt*16 + lrow)*40 + lg*8);
      f32x4 e = MFMA(qfr, bfr, z);
      float si = sinvl[it*64 + mt*16 + lrow];
      #pragma unroll
      for (int r=0;r<4;r++) p[mt*4+r] = exp2f(e[r]) * si;
    }
    #pragma unroll
    for (int r=0;r<4;r++) L[r] += (p[r] + p[4+r]) + (p[8+r] + p[12+r]);
    #pragma unroll
    for (int mt=0; mt<4; mt++){
      #pragma unroll
      for (int r=0;r<4;r++)
        pl[(lg*4+r)*72 + mt*16 + lrow] = f2b(p[mt*4+r]);
    }
    __builtin_amdgcn_s_setprio(1);
    #pragma unroll
    for (int ks=0; ks<2; ks++){
      short8 pa = *(short8*)(pl + lrow*72 + ks*32 + lg*8);
      #pragma unroll
      for (int cf=0; cf<8; cf++){
        short8 vb_ = *(short8*)(vt_t + (cf*16 + lrow)*72 + ks*32 + lg*8);
        acc[cf] = MFMA(pa, vb_, acc[cf]);
      }
    }
    __builtin_amdgcn_s_setprio(0);
    __syncthreads();
    if (it < 7){
      storeT();
      __syncthreads();
    }
  }

  #pragma unroll
  for (int mask=1; mask<16; mask<<=1){
    #pragma unroll
    for (int r=0;r<4;r++) L[r] += __shfl_xor(L[r], mask);
  }

  const long tile = (long)((b*32 + rt)*4 + quarter);
  float* aP = accP + tile*64*128;
  #pragma unroll
  for (int cf=0; cf<8; cf++){
    #pragma unroll
    for (int r=0;r<4;r++)
      aP[(wv*16 + lg*4 + r)*128 + cf*16 + lrow] = acc[cf][r];
  }
  if (lrow == 0){
    #pragma unroll
    for (int r=0;r<4;r++) Lp[tile*64 + wv*16 + lg*4 + r] = L[r];
  }
}

// ---------------- kernel 3b: combine 4 partials + projection + BN + residual ----------------
// grid 512: b(3b) | rowtile(6b of 32 rows). Wave (rh=wv>>1, ch=wv&1).
__global__ __launch_bounds__(256,4) void k_fin(const float* __restrict__ x, const float* __restrict__ accP,
    const float* __restrict__ Lp, const short* __restrict__ wp, const float* __restrict__ scale,
    const float* __restrict__ shift, float* __restrict__ out){
  __shared__ __align__(16) short lds[4352]; // 2 x [16][136]
  const int tid = threadIdx.x;
  const int wv = tid >> 6, l = tid & 63, lrow = l & 15, lg = l >> 4;
  const int b = blockIdx.x >> 6;
  const int rt = blockIdx.x & 63;
  const int rh = wv >> 1, ch = wv & 1;
  const int nb = rt*32 + rh*16;

  float linv[4];
  #pragma unroll
  for (int r=0;r<4;r++){
    const int n = nb + lg*4 + r;
    const long tb = ((long)(b*32 + (n>>6))*4)*64 + (n & 63);
    float Ls = Lp[tb] + Lp[tb+64] + Lp[tb+128] + Lp[tb+192];
    linv[r] = __builtin_amdgcn_rcpf(1e-9f + Ls);
  }

  short* dl = lds + rh*2176;
  float xv[16];
  #pragma unroll
  for (int cf=0; cf<4; cf++){
    #pragma unroll
    for (int r=0;r<4;r++){
      const int n = nb + lg*4 + r;
      const int col = ch*64 + cf*16 + lrow;
      float xx = x[((long)(b*NN + n))*CC + col];
      xv[cf*4+r] = xx;
      const long ab = (((long)(b*32 + (n>>6))*4)*64 + (n & 63))*128 + col;
      float a = accP[ab] + accP[ab + 64*128] + accP[ab + 2*64*128] + accP[ab + 3*64*128];
      dl[(lg*4+r)*136 + col] = f2b(xx - a*linv[r]);
    }
  }
  __syncthreads();

  f32x4 yac[4];
  #pragma unroll
  for (int i=0;i<4;i++) yac[i] = f32x4{0.f,0.f,0.f,0.f};
  #pragma unroll
  for (int ks=0; ks<4; ks++){
    short8 da = *(short8*)(dl + lrow*136 + ks*32 + lg*8);
    #pragma unroll
    for (int of=0; of<4; of++){
      short8 wfr = *(const short8*)(wp + ((ch*4+of)*16 + lrow)*CC + ks*32 + lg*8);
      yac[of] = MFMA(da, wfr, yac[of]);
    }
  }
  float* ob = out + ((long)(b*NN + nb))*CC;
  #pragma unroll
  for (int of=0; of<4; of++){
    const int o = (ch*4+of)*16 + lrow;
    const float sc = scale[o], sh = shift[o];
    #pragma unroll
    for (int r=0;r<4;r++){
      float y = yac[of][r]*sc + sh;
      y = (y >= 0.f) ? y : 0.01f*y;
      ob[(lg*4+r)*CC + o] = y + xv[of*4+r];
    }
  }
}

// ---------------- fallback: monolithic attention (only if ws too small) ----------------
__global__ __launch_bounds__(256) void k_attn_mono(const float* __restrict__ x, const short* __restrict__ qb,
    const short* __restrict__ kb, const short* __restrict__ vt, const float* __restrict__ csum,
    const short* __restrict__ wp, const float* __restrict__ scale, const float* __restrict__ shift,
    float* __restrict__ out){
  __shared__ __align__(16) short lds[28160];
  const int tid = threadIdx.x;
  const int wv = tid >> 6, l = tid & 63, lrow = l & 15, lg = l >> 4;
  const int b = blockIdx.x >> 5;
  const int n0 = (blockIdx.x & 31)*64 + wv*16;
  short8 qfr = *(const short8*)(qb + (long)(b*NN + n0 + lrow)*DD + lg*8);
  const short* kbb = kb + (long)b*NN*DD;
  const short* vtb = vt + (long)b*CC*NN;
  const float* c0 = csum + b*NN;

  f32x4 acc[8];
  #pragma unroll
  for (int i=0;i<8;i++) acc[i] = f32x4{0.f,0.f,0.f,0.f};
  float L[4] = {0.f,0.f,0.f,0.f};
  short8 sv[4]; short8 sk[2];
  const int cr = tid >> 1, hf = tid & 1;
  auto loadT = [&](int m0){
    const short* s = vtb + (long)cr*NN + m0 + hf*32;
    sv[0] = *(const short8*)(s); sv[1] = *(const short8*)(s+8);
    sv[2] = *(const short8*)(s+16); sv[3] = *(const short8*)(s+24);
    if (tid < 128){
      const short* s2 = kbb + (long)(m0 + cr)*DD + hf*16;
      sk[0] = *(const short8*)(s2); sk[1] = *(const short8*)(s2+8);
    }
  };
  auto storeT = [&](int buf){
    short* vt_t = lds + buf*11776;
    *(short8*)(vt_t + cr*72 + hf*32 + 0)  = sv[0];
    *(short8*)(vt_t + cr*72 + hf*32 + 8)  = sv[1];
    *(short8*)(vt_t + cr*72 + hf*32 + 16) = sv[2];
    *(short8*)(vt_t + cr*72 + hf*32 + 24) = sv[3];
    if (tid < 128){
      short* kb_t = vt_t + 9216;
      *(short8*)(kb_t + cr*40 + hf*16 + 0) = sk[0];
      *(short8*)(kb_t + cr*40 + hf*16 + 8) = sk[1];
    }
  };
  loadT(0); storeT(0); __syncthreads();
  short* pl = lds + 23552 + wv*1152;
  f32x4 z = {0.f,0.f,0.f,0.f};
  for (int it=0; it<32; it++){
    const int m0 = it*64;
    const int cur = it & 1;
    if (it < 31) loadT(m0 + 64);
    short* vt_t = lds + cur*11776;
    short* kb_t = vt_t + 9216;
    float p[16];
    #pragma unroll
    for (int mt=0; mt<4; mt++){
      short8 bfr = *(short8*)(kb_t + (mt*16 + lrow)*40 + lg*8);
      f32x4 e = MFMA(qfr, bfr, z);
      const int m = m0 + mt*16 + lrow;
      float si = __builtin_amdgcn_rcpf(c0[m] + c0[m+BB*NN] + c0[m+2*BB*NN] + c0[m+3*BB*NN]);
      #pragma unroll
      for (int r=0;r<4;r++) p[mt*4+r] = exp2f(e[r]) * si;
    }
    #pragma unroll
    for (int r=0;r<4;r++) L[r] += (p[r] + p[4+r]) + (p[8+r] + p[12+r]);
    #pragma unroll
    for (int mt=0; mt<4; mt++){
      #pragma unroll
      for (int r=0;r<4;r++)
        pl[(lg*4+r)*72 + mt*16 + lrow] = f2b(p[mt*4+r]);
    }
    #pragma unroll
    for (int ks=0; ks<2; ks++){
      short8 pa = *(short8*)(pl + lrow*72 + ks*32 + lg*8);
      #pragma unroll
      for (int cf=0; cf<8; cf++){
        short8 vb_ = *(short8*)(vt_t + (cf*16 + lrow)*72 + ks*32 + lg*8);
        acc[cf] = MFMA(pa, vb_, acc[cf]);
      }
    }
    if (it < 31) storeT((it+1) & 1);
    __syncthreads();
  }
  #pragma unroll
  for (int mask=1; mask<16; mask<<=1){
    #pragma unroll
    for (int r=0;r<4;r++) L[r] += __shfl_xor(L[r], mask);
  }
  float linv[4];
  #pragma unroll
  for (int r=0;r<4;r++) linv[r] = __builtin_amdgcn_rcpf(1e-9f + L[r]);
  const float* xbb = x + (long)(b*NN + n0)*CC;
  float xv[32];
  short* dl = lds + wv*2176;
  #pragma unroll
  for (int cf=0; cf<8; cf++){
    #pragma unroll
    for (int r=0;r<4;r++){
      float xx = xbb[(lg*4+r)*CC + cf*16 + lrow];
      xv[cf*4+r] = xx;
      dl[(lg*4+r)*136 + cf*16 + lrow] = f2b(xx - acc[cf][r]*linv[r]);
    }
  }
  f32x4 yac[8];
  #pragma unroll
  for (int i=0;i<8;i++) yac[i] = f32x4{0.f,0.f,0.f,0.f};
  #pragma unroll
  for (int ks=0; ks<4; ks++){
    short8 da = *(short8*)(dl + lrow*136 + ks*32 + lg*8);
    #pragma unroll
    for (int of=0; of<8; of++){
      short8 wfr = *(const short8*)(wp + (of*16 + lrow)*CC + ks*32 + lg*8);
      yac[of] = MFMA(da, wfr, yac[of]);
    }
  }
  float* ob = out + (long)(b*NN + n0)*CC;
  #pragma unroll
  for (int of=0; of<8; of++){
    const int o = of*16 + lrow;
    const float sc = scale[o], sh = shift[o];
    #pragma unroll
    for (int r=0;r<4;r++){
      float y = yac[of][r]*sc + sh;
      y = (y >= 0.f) ? y : 0.01f*y;
      ob[(lg*4+r)*CC + o] = y + xv[of*4+r];
    }
  }
}

extern "C" void kernel_launch(void* const* d_in, const int* in_sizes, int n_in,
                              void* d_out, int out_size, void* d_ws, size_t ws_size,
                              hipStream_t stream) {
  const float* x  = (const float*)d_in[0];
  const float* Wq = (const float*)d_in[1];
  const float* Wk = (const float*)d_in[2];
  const float* Wv = (const float*)d_in[3];
  const float* Wp = (const float*)d_in[4];
  const float* g  = (const float*)d_in[5];
  const float* bt = (const float*)d_in[6];
  const float* mu = (const float*)d_in[7];
  const float* vr = (const float*)d_in[8];
  float* out = (float*)d_out;

  char* ws = (char*)d_ws;
  short* wqkv  = (short*)(ws + 0);                  // 49152
  short* wp    = (short*)(ws + 49152);              // 32768
  float* scale = (float*)(ws + 81920);              // 512
  float* shift = (float*)(ws + 82432);              // 512
  short* qb    = (short*)(ws + 98304);              // 1 MB
  short* kb    = (short*)(ws + 1146880);            // 1 MB
  short* vt    = (short*)(ws + 2195456);            // 4 MB
  float* csum  = (float*)(ws + 6389760);            // 4*16384*4 = 262144
  float* Lp    = (float*)(ws + 6651904);            // 1024*64*4 = 262144
  float* accP  = (float*)(ws + 6914048);            // 1024*64*128*4 = 33.55 MB
  const size_t need_split = 6914048 + 33554432;

  k_pack<<<96, 256, 0, stream>>>(Wq, Wk, Wv, Wp, g, bt, mu, vr, wqkv, wp, scale, shift);
  k_qkv<<<512, 256, 0, stream>>>(x, wqkv, qb, kb, vt);
  k_colsum<<<1024, 256, 0, stream>>>(qb, kb, csum);
  if (ws_size >= need_split){
    k_attn<<<1024, 256, 0, stream>>>(qb, kb, vt, csum, accP, Lp);
    k_fin<<<512, 256, 0, stream>>>(x, accP, Lp, wp, scale, shift, out);
  } else {
    k_attn_mono<<<256, 256, 0, stream>>>(x, qb, kb, vt, csum, wp, scale, shift, out);
  }
}

// Round 6
// 131.158 us; speedup vs baseline: 1.2277x; 1.0207x over previous
//
#include <hip/hip_runtime.h>
#include <stdint.h>

#define BB 8
#define NN 2048
#define CC 128
#define DD 32
#define LOG2E 1.44269504088896340736f

typedef __attribute__((ext_vector_type(8))) short short8;
typedef __attribute__((ext_vector_type(4))) short short4v;
typedef __attribute__((ext_vector_type(4))) float f32x4;

#define MFMA(a,b,c) __builtin_amdgcn_mfma_f32_16x16x32_bf16(a,b,c,0,0,0)

__device__ __forceinline__ short f2b(float f){
  uint32_t u = __float_as_uint(f);
  uint32_t r = (u + 0x7fffu + ((u >> 16) & 1u)) >> 16;
  return (short)r;
}
__device__ __forceinline__ float b2f(short s){
  uint32_t u = ((uint32_t)(uint16_t)s) << 16;
  return __uint_as_float(u);
}

// ---------------- kernel 0: pack weights, fold BN ----------------
__global__ void k_pack(const float* __restrict__ Wq, const float* __restrict__ Wk,
                       const float* __restrict__ Wv, const float* __restrict__ Wp,
                       const float* __restrict__ g, const float* __restrict__ bt,
                       const float* __restrict__ mu, const float* __restrict__ vr,
                       short* __restrict__ wqkv, short* __restrict__ wp,
                       float* __restrict__ scale, float* __restrict__ shift){
  int i = blockIdx.x*256 + threadIdx.x;
  if (i < 192*128){
    int r = i >> 7, c = i & 127;
    float w = (r < 32) ? Wq[r*128+c] : (r < 64) ? Wk[(r-32)*128+c] : Wv[(r-64)*128+c];
    wqkv[i] = f2b(w);
  }
  if (i < 128*128) wp[i] = f2b(Wp[i]);
  if (i < 128){
    float s = g[i] * rsqrtf(vr[i] + 1e-5f);
    scale[i] = s;
    shift[i] = bt[i] - mu[i]*s;
  }
}

// ---------------- kernel 1: QKV projections, grid 1024 (16 rows/block, wave=3 outputs) ----------------
// qb is pre-scaled by LOG2E so downstream uses exp2 directly.
__global__ __launch_bounds__(256,4) void k_qkv(const float* __restrict__ x, const short* __restrict__ wqkv,
    short* __restrict__ qb, short* __restrict__ kb, short* __restrict__ vt){
  const int tid = threadIdx.x;
  const int wv = tid >> 6, l = tid & 63, lrow = l & 15, lg = l >> 4;
  const int r0 = blockIdx.x*16;
  const int base = wv*3;
  const float* xr = x + (long)(r0 + lrow)*CC;
  short8 a[4];
  #pragma unroll
  for (int ks=0; ks<4; ks++){
    f32x4 u0 = *(const f32x4*)(xr + ks*32 + lg*8);
    f32x4 u1 = *(const f32x4*)(xr + ks*32 + lg*8 + 4);
    short8 t;
    #pragma unroll
    for (int j=0;j<4;j++){ t[j] = f2b(u0[j]); t[4+j] = f2b(u1[j]); }
    a[ks] = t;
  }
  f32x4 acc[3];
  #pragma unroll
  for (int i=0;i<3;i++) acc[i] = f32x4{0.f,0.f,0.f,0.f};
  #pragma unroll
  for (int of=0; of<3; of++){
    #pragma unroll
    for (int ks=0; ks<4; ks++){
      short8 bfr = *(const short8*)(wqkv + ((base+of)*16 + lrow)*CC + ks*32 + lg*8);
      acc[of] = MFMA(a[ks], bfr, acc[of]);
    }
  }
  const int b = r0 / NN, nin = r0 % NN;
  #pragma unroll
  for (int of=0; of<3; of++){
    const int oo = base + of;
    const int o = oo*16 + lrow;
    if (oo < 2){
      #pragma unroll
      for (int rr=0; rr<4; rr++) qb[(long)(r0 + lg*4 + rr)*DD + o] = f2b(acc[of][rr]*LOG2E);
    } else if (oo < 4){
      #pragma unroll
      for (int rr=0; rr<4; rr++) kb[(long)(r0 + lg*4 + rr)*DD + (o-32)] = f2b(acc[of][rr]);
    } else {
      short4v s;
      #pragma unroll
      for (int rr=0; rr<4; rr++) s[rr] = f2b(acc[of][rr]);
      *(short4v*)(vt + (long)(b*CC + (o-64))*NN + nin + lg*4) = s;
    }
  }
}

// ---------------- kernel 2: column sums of exp(E), 4-way n-split, XCD-affine ----------------
// grid 1024: id = (b*4+q) + mb*32  → all blocks sharing (b,q) on one XCD
__global__ __launch_bounds__(256,4) void k_colsum(const short* __restrict__ qb, const short* __restrict__ kb,
                                                  float* __restrict__ csum){
  const int tid = threadIdx.x;
  const int wv = tid >> 6, l = tid & 63, lrow = l & 15, lg = l >> 4;
  const int bq = blockIdx.x & 31;
  const int b = bq >> 2, q = bq & 3;
  const int m0 = (blockIdx.x >> 5)*64 + wv*16;
  short8 afr = *(const short8*)(kb + (long)(b*NN + m0 + lrow)*DD + lg*8);
  const short* qbase = qb + (long)b*NN*DD;
  float sum[4] = {0.f,0.f,0.f,0.f};
  f32x4 z = {0.f,0.f,0.f,0.f};
  const int nbeg = q*512, nend = nbeg + 512;
  #pragma unroll 4
  for (int n0=nbeg; n0<nend; n0+=16){
    short8 bfr = *(const short8*)(qbase + (long)(n0 + lrow)*DD + lg*8);
    f32x4 e = MFMA(afr, bfr, z);
    #pragma unroll
    for (int r=0;r<4;r++) sum[r] += exp2f(e[r]);
  }
  #pragma unroll
  for (int mask=1; mask<16; mask<<=1){
    #pragma unroll
    for (int r=0;r<4;r++) sum[r] += __shfl_xor(sum[r], mask);
  }
  if (lrow == 0){
    #pragma unroll
    for (int r=0;r<4;r++) csum[q*(BB*NN) + b*NN + m0 + lg*4 + r] = sum[r];
  }
}

// ---------------- kernel 3a: attention pass, 4-way key split, XCD-affine ----------------
// grid 1024: id = (b*4+q) + rt*32. Partial acc stored bf16 [tile][row][128].
__global__ __launch_bounds__(256,4) void k_attn(const short* __restrict__ qb,
    const short* __restrict__ kb, const short* __restrict__ vt, const float* __restrict__ csum,
    short* __restrict__ accPb, float* __restrict__ Lp){
  __shared__ __align__(16) short lds[17408]; // tile 11776 + P 4*1152 + sinv 1024
  const int tid = threadIdx.x;
  const int wv = tid >> 6, l = tid & 63, lrow = l & 15, lg = l >> 4;
  const int bq = blockIdx.x & 31;
  const int b = bq >> 2;
  const int quarter = bq & 3;
  const int rt = blockIdx.x >> 5;
  const int n0 = rt*64 + wv*16;
  short8 qfr = *(const short8*)(qb + (long)(b*NN + n0 + lrow)*DD + lg*8);
  const short* kbb = kb + (long)b*NN*DD;
  const short* vtb = vt + (long)b*CC*NN;
  float* sinvl = (float*)(lds + 16384);

  // combine 4 csum parts for this block's 512 keys into LDS
  const int mbase = quarter*512;
  {
    const float* c0 = csum + b*NN + mbase;
    #pragma unroll
    for (int i=tid; i<512; i+=256){
      float s = c0[i] + c0[i + BB*NN] + c0[i + 2*BB*NN] + c0[i + 3*BB*NN];
      sinvl[i] = __builtin_amdgcn_rcpf(s);
    }
  }

  f32x4 acc[8];
  #pragma unroll
  for (int i=0;i<8;i++) acc[i] = f32x4{0.f,0.f,0.f,0.f};
  float L[4] = {0.f,0.f,0.f,0.f};

  short8 sv[4]; short8 sk[2];
  const int cr = tid >> 1, hf = tid & 1;

  auto loadT = [&](int m0){
    const short* s = vtb + (long)cr*NN + m0 + hf*32;
    sv[0] = *(const short8*)(s);
    sv[1] = *(const short8*)(s+8);
    sv[2] = *(const short8*)(s+16);
    sv[3] = *(const short8*)(s+24);
    if (tid < 128){
      const short* s2 = kbb + (long)(m0 + cr)*DD + hf*16;
      sk[0] = *(const short8*)(s2);
      sk[1] = *(const short8*)(s2+8);
    }
  };
  auto storeT = [&](){
    short* vt_t = lds;
    *(short8*)(vt_t + cr*72 + hf*32 + 0)  = sv[0];
    *(short8*)(vt_t + cr*72 + hf*32 + 8)  = sv[1];
    *(short8*)(vt_t + cr*72 + hf*32 + 16) = sv[2];
    *(short8*)(vt_t + cr*72 + hf*32 + 24) = sv[3];
    if (tid < 128){
      short* kb_t = vt_t + 9216;
      *(short8*)(kb_t + cr*40 + hf*16 + 0) = sk[0];
      *(short8*)(kb_t + cr*40 + hf*16 + 8) = sk[1];
    }
  };

  loadT(mbase);
  storeT();
  __syncthreads();

  short* pl = lds + 11776 + wv*1152;
  f32x4 z = {0.f,0.f,0.f,0.f};
  for (int it=0; it<8; it++){
    const int m0 = mbase + it*64;
    if (it < 7) loadT(m0 + 64);
    short* vt_t = lds;
    short* kb_t = lds + 9216;
    float p[16];
    #pragma unroll
    for (int mt=0; mt<4; mt++){
      short8 bfr = *(short8*)(kb_t + (mt*16 + lrow)*40 + lg*8);
      f32x4 e = MFMA(qfr, bfr, z);
      float si = sinvl[it*64 + mt*16 + lrow];
      #pragma unroll
      for (int r=0;r<4;r++) p[mt*4+r] = exp2f(e[r]) * si;
    }
    #pragma unroll
    for (int r=0;r<4;r++) L[r] += (p[r] + p[4+r]) + (p[8+r] + p[12+r]);
    #pragma unroll
    for (int mt=0; mt<4; mt++){
      #pragma unroll
      for (int r=0;r<4;r++)
        pl[(lg*4+r)*72 + mt*16 + lrow] = f2b(p[mt*4+r]);
    }
    __builtin_amdgcn_s_setprio(1);
    #pragma unroll
    for (int ks=0; ks<2; ks++){
      short8 pa = *(short8*)(pl + lrow*72 + ks*32 + lg*8);
      #pragma unroll
      for (int cf=0; cf<8; cf++){
        short8 vb_ = *(short8*)(vt_t + (cf*16 + lrow)*72 + ks*32 + lg*8);
        acc[cf] = MFMA(pa, vb_, acc[cf]);
      }
    }
    __builtin_amdgcn_s_setprio(0);
    __syncthreads();
    if (it < 7){
      storeT();
      __syncthreads();
    }
  }

  #pragma unroll
  for (int mask=1; mask<16; mask<<=1){
    #pragma unroll
    for (int r=0;r<4;r++) L[r] += __shfl_xor(L[r], mask);
  }

  const long tile = (long)((b*32 + rt)*4 + quarter);
  short* aP = accPb + tile*64*128;
  #pragma unroll
  for (int cf=0; cf<8; cf++){
    #pragma unroll
    for (int r=0;r<4;r++)
      aP[(wv*16 + lg*4 + r)*128 + cf*16 + lrow] = f2b(acc[cf][r]);
  }
  if (lrow == 0){
    #pragma unroll
    for (int r=0;r<4;r++) Lp[tile*64 + wv*16 + lg*4 + r] = L[r];
  }
}

// ---------------- kernel 3b: combine 4 bf16 partials + projection + BN + residual ----------------
// grid 1024: b(3b) | rt(7b of 16 rows). Vectorized loads; waves split output cols.
__global__ __launch_bounds__(256,4) void k_fin(const float* __restrict__ x, const short* __restrict__ accPb,
    const float* __restrict__ Lp, const short* __restrict__ wp, const float* __restrict__ scale,
    const float* __restrict__ shift, float* __restrict__ out){
  __shared__ __align__(16) short dl[16*136];   // [16 rows][136]
  __shared__ float linv_s[16];
  const int tid = threadIdx.x;
  const int wv = tid >> 6, l = tid & 63, lrow = l & 15, lg = l >> 4;
  const int b = blockIdx.x >> 7;
  const int rt = blockIdx.x & 127;
  const int nb = rt*16;
  const long tileIdx = (long)(b*32 + (rt>>2))*4;
  const int rowoff = (rt&3)*16;

  if (tid < 16){
    float Ls = Lp[(tileIdx+0)*64 + rowoff + tid] + Lp[(tileIdx+1)*64 + rowoff + tid]
             + Lp[(tileIdx+2)*64 + rowoff + tid] + Lp[(tileIdx+3)*64 + rowoff + tid];
    linv_s[tid] = __builtin_amdgcn_rcpf(1e-9f + Ls);
  }

  const int row_l = tid >> 4;
  const int c0 = (tid & 15)*8;
  float a[8];
  #pragma unroll
  for (int j=0;j<8;j++) a[j] = 0.f;
  #pragma unroll
  for (int p=0;p<4;p++){
    short8 v = *(const short8*)(accPb + (tileIdx+p)*64*128 + (rowoff+row_l)*128 + c0);
    #pragma unroll
    for (int j=0;j<8;j++) a[j] += b2f(v[j]);
  }
  const float* xr = x + ((long)(b*NN + nb + row_l))*CC + c0;
  f32x4 x0 = *(const f32x4*)(xr);
  f32x4 x1 = *(const f32x4*)(xr + 4);
  __syncthreads();
  {
    const float li = linv_s[row_l];
    short4v d0, d1;
    #pragma unroll
    for (int j=0;j<4;j++){
      d0[j] = f2b(x0[j] - a[j]*li);
      d1[j] = f2b(x1[j] - a[4+j]*li);
    }
    *(short4v*)(dl + row_l*136 + c0) = d0;
    *(short4v*)(dl + row_l*136 + c0 + 4) = d1;
  }
  __syncthreads();

  f32x4 yac[2];
  yac[0] = f32x4{0.f,0.f,0.f,0.f};
  yac[1] = f32x4{0.f,0.f,0.f,0.f};
  #pragma unroll
  for (int ks=0; ks<4; ks++){
    short8 da = *(short8*)(dl + lrow*136 + ks*32 + lg*8);
    #pragma unroll
    for (int of=0; of<2; of++){
      short8 wfr = *(const short8*)(wp + ((wv*2+of)*16 + lrow)*CC + ks*32 + lg*8);
      yac[of] = MFMA(da, wfr, yac[of]);
    }
  }
  float* ob = out + ((long)(b*NN + nb))*CC;
  const float* xb = x + ((long)(b*NN + nb))*CC;
  #pragma unroll
  for (int of=0; of<2; of++){
    const int o = (wv*2+of)*16 + lrow;
    const float sc = scale[o], sh = shift[o];
    #pragma unroll
    for (int r=0;r<4;r++){
      float y = yac[of][r]*sc + sh;
      y = (y >= 0.f) ? y : 0.01f*y;
      ob[(lg*4+r)*CC + o] = y + xb[(lg*4+r)*CC + o];
    }
  }
}

// ---------------- fallback: monolithic attention (only if ws too small) ----------------
__global__ __launch_bounds__(256) void k_attn_mono(const float* __restrict__ x, const short* __restrict__ qb,
    const short* __restrict__ kb, const short* __restrict__ vt, const float* __restrict__ csum,
    const short* __restrict__ wp, const float* __restrict__ scale, const float* __restrict__ shift,
    float* __restrict__ out){
  __shared__ __align__(16) short lds[28160];
  const int tid = threadIdx.x;
  const int wv = tid >> 6, l = tid & 63, lrow = l & 15, lg = l >> 4;
  const int b = blockIdx.x >> 5;
  const int n0 = (blockIdx.x & 31)*64 + wv*16;
  short8 qfr = *(const short8*)(qb + (long)(b*NN + n0 + lrow)*DD + lg*8);
  const short* kbb = kb + (long)b*NN*DD;
  const short* vtb = vt + (long)b*CC*NN;
  const float* c0 = csum + b*NN;

  f32x4 acc[8];
  #pragma unroll
  for (int i=0;i<8;i++) acc[i] = f32x4{0.f,0.f,0.f,0.f};
  float L[4] = {0.f,0.f,0.f,0.f};
  short8 sv[4]; short8 sk[2];
  const int cr = tid >> 1, hf = tid & 1;
  auto loadT = [&](int m0){
    const short* s = vtb + (long)cr*NN + m0 + hf*32;
    sv[0] = *(const short8*)(s); sv[1] = *(const short8*)(s+8);
    sv[2] = *(const short8*)(s+16); sv[3] = *(const short8*)(s+24);
    if (tid < 128){
      const short* s2 = kbb + (long)(m0 + cr)*DD + hf*16;
      sk[0] = *(const short8*)(s2); sk[1] = *(const short8*)(s2+8);
    }
  };
  auto storeT = [&](int buf){
    short* vt_t = lds + buf*11776;
    *(short8*)(vt_t + cr*72 + hf*32 + 0)  = sv[0];
    *(short8*)(vt_t + cr*72 + hf*32 + 8)  = sv[1];
    *(short8*)(vt_t + cr*72 + hf*32 + 16) = sv[2];
    *(short8*)(vt_t + cr*72 + hf*32 + 24) = sv[3];
    if (tid < 128){
      short* kb_t = vt_t + 9216;
      *(short8*)(kb_t + cr*40 + hf*16 + 0) = sk[0];
      *(short8*)(kb_t + cr*40 + hf*16 + 8) = sk[1];
    }
  };
  loadT(0); storeT(0); __syncthreads();
  short* pl = lds + 23552 + wv*1152;
  f32x4 z = {0.f,0.f,0.f,0.f};
  for (int it=0; it<32; it++){
    const int m0 = it*64;
    const int cur = it & 1;
    if (it < 31) loadT(m0 + 64);
    short* vt_t = lds + cur*11776;
    short* kb_t = vt_t + 9216;
    float p[16];
    #pragma unroll
    for (int mt=0; mt<4; mt++){
      short8 bfr = *(short8*)(kb_t + (mt*16 + lrow)*40 + lg*8);
      f32x4 e = MFMA(qfr, bfr, z);
      const int m = m0 + mt*16 + lrow;
      float si = __builtin_amdgcn_rcpf(c0[m] + c0[m+BB*NN] + c0[m+2*BB*NN] + c0[m+3*BB*NN]);
      #pragma unroll
      for (int r=0;r<4;r++) p[mt*4+r] = exp2f(e[r]) * si;
    }
    #pragma unroll
    for (int r=0;r<4;r++) L[r] += (p[r] + p[4+r]) + (p[8+r] + p[12+r]);
    #pragma unroll
    for (int mt=0; mt<4; mt++){
      #pragma unroll
      for (int r=0;r<4;r++)
        pl[(lg*4+r)*72 + mt*16 + lrow] = f2b(p[mt*4+r]);
    }
    #pragma unroll
    for (int ks=0; ks<2; ks++){
      short8 pa = *(short8*)(pl + lrow*72 + ks*32 + lg*8);
      #pragma unroll
      for (int cf=0; cf<8; cf++){
        short8 vb_ = *(short8*)(vt_t + (cf*16 + lrow)*72 + ks*32 + lg*8);
        acc[cf] = MFMA(pa, vb_, acc[cf]);
      }
    }
    if (it < 31) storeT((it+1) & 1);
    __syncthreads();
  }
  #pragma unroll
  for (int mask=1; mask<16; mask<<=1){
    #pragma unroll
    for (int r=0;r<4;r++) L[r] += __shfl_xor(L[r], mask);
  }
  float linv[4];
  #pragma unroll
  for (int r=0;r<4;r++) linv[r] = __builtin_amdgcn_rcpf(1e-9f + L[r]);
  const float* xbb = x + (long)(b*NN + n0)*CC;
  float xv[32];
  short* dl = lds + wv*2176;
  #pragma unroll
  for (int cf=0; cf<8; cf++){
    #pragma unroll
    for (int r=0;r<4;r++){
      float xx = xbb[(lg*4+r)*CC + cf*16 + lrow];
      xv[cf*4+r] = xx;
      dl[(lg*4+r)*136 + cf*16 + lrow] = f2b(xx - acc[cf][r]*linv[r]);
    }
  }
  f32x4 yac[8];
  #pragma unroll
  for (int i=0;i<8;i++) yac[i] = f32x4{0.f,0.f,0.f,0.f};
  #pragma unroll
  for (int ks=0; ks<4; ks++){
    short8 da = *(short8*)(dl + lrow*136 + ks*32 + lg*8);
    #pragma unroll
    for (int of=0; of<8; of++){
      short8 wfr = *(const short8*)(wp + (of*16 + lrow)*CC + ks*32 + lg*8);
      yac[of] = MFMA(da, wfr, yac[of]);
    }
  }
  float* ob = out + (long)(b*NN + n0)*CC;
  #pragma unroll
  for (int of=0; of<8; of++){
    const int o = of*16 + lrow;
    const float sc = scale[o], sh = shift[o];
    #pragma unroll
    for (int r=0;r<4;r++){
      float y = yac[of][r]*sc + sh;
      y = (y >= 0.f) ? y : 0.01f*y;
      ob[(lg*4+r)*CC + o] = y + xv[of*4+r];
    }
  }
}

extern "C" void kernel_launch(void* const* d_in, const int* in_sizes, int n_in,
                              void* d_out, int out_size, void* d_ws, size_t ws_size,
                              hipStream_t stream) {
  const float* x  = (const float*)d_in[0];
  const float* Wq = (const float*)d_in[1];
  const float* Wk = (const float*)d_in[2];
  const float* Wv = (const float*)d_in[3];
  const float* Wp = (const float*)d_in[4];
  const float* g  = (const float*)d_in[5];
  const float* bt = (const float*)d_in[6];
  const float* mu = (const float*)d_in[7];
  const float* vr = (const float*)d_in[8];
  float* out = (float*)d_out;

  char* ws = (char*)d_ws;
  short* wqkv  = (short*)(ws + 0);                  // 49152
  short* wp    = (short*)(ws + 49152);              // 32768
  float* scale = (float*)(ws + 81920);              // 512
  float* shift = (float*)(ws + 82432);              // 512
  short* qb    = (short*)(ws + 98304);              // 1 MB
  short* kb    = (short*)(ws + 1146880);            // 1 MB
  short* vt    = (short*)(ws + 2195456);            // 4 MB
  float* csum  = (float*)(ws + 6389760);            // 4*16384*4 = 262144
  float* Lp    = (float*)(ws + 6651904);            // 1024*64*4 = 262144
  short* accPb = (short*)(ws + 6914048);            // 1024*64*128*2 = 16.78 MB
  const size_t need_split = 6914048 + 16777216;

  k_pack<<<96, 256, 0, stream>>>(Wq, Wk, Wv, Wp, g, bt, mu, vr, wqkv, wp, scale, shift);
  k_qkv<<<1024, 256, 0, stream>>>(x, wqkv, qb, kb, vt);
  k_colsum<<<1024, 256, 0, stream>>>(qb, kb, csum);
  if (ws_size >= need_split){
    k_attn<<<1024, 256, 0, stream>>>(qb, kb, vt, csum, accPb, Lp);
    k_fin<<<1024, 256, 0, stream>>>(x, accPb, Lp, wp, scale, shift, out);
  } else {
    k_attn_mono<<<256, 256, 0, stream>>>(x, qb, kb, vt, csum, wp, scale, shift, out);
  }
}